// Round 6
// baseline (509.034 us; speedup 1.0000x reference)
//
#include <hip/hip_runtime.h>

typedef _Float16 half8_t __attribute__((ext_vector_type(8)));
typedef _Float16 half4_t __attribute__((ext_vector_type(4)));
typedef float floatx4 __attribute__((ext_vector_type(4)));
typedef float f32x16 __attribute__((ext_vector_type(16)));

// async global->LDS, 16B per lane. lds ptr wave-uniform; HW writes lane L at
// ldsbase + L*16.
__device__ inline void gload16(const void* g, void* l) {
  __builtin_amdgcn_global_load_lds(
      (const __attribute__((address_space(1))) unsigned int*)g,
      (__attribute__((address_space(3))) unsigned int*)l, 16, 0, 0);
}

// ================== 256x256 BT GEMM, 32x32x16 MFMA =======================
// C[m,n] = sum_h A[m,h]*B[n,h] (+bias). K=1024 = 16 tiles of BK=64.
// 512 threads = 8 waves in 2(wr) x 4(wc); per phase all waves compute one
// 128x128 C-quadrant; per-wave slice 64x32 per quadrant.
// LDS per operand per parity: 256 rows x 64 k fp16 chunk-transposed:
// 16B chunk (kb,m) at offset (kb*256+m)*16, kb = k/8. Conflict-free for
// linear gload_lds and for frag reads (consecutive chunks per lane group).
// Fragments (32x32x16): lane L (lo=L&31, hi=L>>5):
//   A-frag: A[row0+lo][ks*16 + hi*8 + j]  -> chunk(ks*2+hi, row0+lo)
//   B-frag: B[col0+lo][ks*16 + hi*8 + j]  -> chunk(ks*2+hi, col0+lo)
//   C/D: col = lo, row = (e&3) + 8*(e>>2) + 4*hi   [m74/m101]
// Phases (r2 skeleton, Gray quadrant order; af reused P1->P2, bf1 P2->P3,
// bf0 kept in regs P1->P4 -- no LDS re-read):
//   P1 Q00: lda A0->af, ldb B0->bf0; stage B-h0(t+1)->q
//   P2 Q01: ldb B1->bf1;             A-stage slot (A0 dead)
//   P3 Q11: lda A1->af;              stage B-h1(t+2)->p (B1 dead)
//   P4 Q10: (no frag reads)          A-stage slot (A1 dead) + vmcnt
// fp16-A path (ACVT=0): A staged via gload_lds at P2(h0)/P4(h1); vmcnt(6)
//   at P4 (r2's proven ledger).
// fp32-A path (ACVT=1): P2 issues 8 global_load_dwordx4 (tile t+2, fp32);
//   P4: vmcnt(2) [drains the 8 A-loads AND P1's B gloads; keeps P3's 2],
//   cvt->fp16, 8 ds_write_b128 into A[p] (both halves dead by P4).
// NOTE (r5 fix): meme/text are SEPARATE allocations -> Q-proj and K-proj
// are separate launches (bz=0); never stride across input buffers.
constexpr int NT = 16;  // K / 64

template <int MH>
__device__ inline void lda_frags(const char* sA, int wr, int lo, int hi,
                                 half8_t af[2][4]) {
#pragma unroll
  for (int mp = 0; mp < 2; ++mp)
#pragma unroll
    for (int ks = 0; ks < 4; ++ks)
      af[mp][ks] = *(const half8_t*)(
          sA + (size_t)(((ks * 2 + hi) * 256 + MH * 128 + wr * 64 + mp * 32 +
                         lo) << 4));
}

template <int NH>
__device__ inline void ldb_frags(const char* sB, int wc, int lo, int hi,
                                 half8_t bf[4]) {
#pragma unroll
  for (int ks = 0; ks < 4; ++ks)
    bf[ks] = *(const half8_t*)(
        sB + (size_t)(((ks * 2 + hi) * 256 + NH * 128 + wc * 32 + lo) << 4));
}

// one C-quadrant: 2 m-pos x 4 k-steps of 32x32x16
template <int MQ, int NI>
__device__ inline void mfma_quad(const half8_t af[2][4], const half8_t bf[4],
                                 f32x16 acc[4][2]) {
  __builtin_amdgcn_s_setprio(1);
#pragma unroll
  for (int mp = 0; mp < 2; ++mp)
#pragma unroll
    for (int ks = 0; ks < 4; ++ks)
      acc[MQ + mp][NI] = __builtin_amdgcn_mfma_f32_32x32x16_f16(
          af[mp][ks], bf[ks], acc[MQ + mp][NI], 0, 0, 0);
  __builtin_amdgcn_s_setprio(0);
}

// stage half h (rows [h*128,h*128+128)) of K-tile u of fp16 operand X (X
// already includes the block tile offset). wave wid covers kb=wid.
__device__ inline void stage_half(const _Float16* __restrict__ X, int ldx,
                                  int u, char* opbase, int h, int wid,
                                  int lane) {
#pragma unroll
  for (int i = 0; i < 2; ++i) {
    gload16(X + (long)(h * 128 + i * 64 + lane) * ldx + u * 64 + wid * 8,
            opbase + (size_t)((wid * 256 + h * 128 + i * 64) << 4));
  }
}

// fp32-A reg-staging: issue 8 loads for the FULL 256-row tile of K-tile u.
__device__ inline void a32_issue(const float* __restrict__ X, int ldx, int u,
                                 int wid, int lane, floatx4 va[4][2]) {
#pragma unroll
  for (int hj = 0; hj < 4; ++hj) {
    const float* src =
        X + (long)((hj >> 1) * 128 + (hj & 1) * 64 + lane) * ldx + u * 64 +
        wid * 8;
    va[hj][0] = *(const floatx4*)(src);
    va[hj][1] = *(const floatx4*)(src + 4);
  }
}

// after vmcnt wait: convert (RTE) + ds_write_b128 into both A halves.
__device__ inline void a32_write(char* opbase, int wid, int lane,
                                 const floatx4 va[4][2]) {
#pragma unroll
  for (int hj = 0; hj < 4; ++hj) {
    half8_t h = {(_Float16)va[hj][0][0], (_Float16)va[hj][0][1],
                 (_Float16)va[hj][0][2], (_Float16)va[hj][0][3],
                 (_Float16)va[hj][1][0], (_Float16)va[hj][1][1],
                 (_Float16)va[hj][1][2], (_Float16)va[hj][1][3]};
    *(half8_t*)(opbase +
                (size_t)((wid * 256 + (hj >> 1) * 128 + (hj & 1) * 64 + lane)
                         << 4)) = h;
  }
}

template <typename OT, int BIAS, int GX, int GY, int ACVT>
__global__ __launch_bounds__(512, 2) void gemm256(
    const _Float16* __restrict__ A, const float* __restrict__ A32, long As,
    int lda, const _Float16* __restrict__ B, long Bs, int ldb,
    OT* __restrict__ C, long Cs, int ldc, const float* __restrict__ bias,
    int biasStride) {
  __shared__ char smem[131072];  // A: p*32768, B: 65536 + p*32768

  // XCD chunk swizzle (grids are 256, always %8==0)
  const int id = blockIdx.x;
  const int chunk = gridDim.x >> 3;
  const int nid = (id & 7) * chunk + (id >> 3);
  const int bx = nid % GX;
  const int by = (nid / GX) % GY;
  const int bz = nid / (GX * GY);

  const int tid = threadIdx.x;
  const int lane = tid & 63;
  const int wid = tid >> 6;
  const int wr = wid >> 2;   // 0..1
  const int wc = wid & 3;    // 0..3
  const int lo = lane & 31;
  const int hi = lane >> 5;
  const long m0 = (long)by * 256;
  const long n0 = (long)bx * 256;
  const _Float16* Ab = A;
  const float* A32b = A32;
  if constexpr (ACVT) A32b += (long)bz * As + m0 * (long)lda;
  else Ab += (long)bz * As + m0 * (long)lda;
  const _Float16* Bb = B + (long)bz * Bs + n0 * (long)ldb;
  C += (long)bz * Cs;

  f32x16 acc[4][2] = {};
  half8_t af[2][4], bf0[4], bf1[4];
  floatx4 va[4][2];

  char* sA0 = smem;
  char* sA1 = smem + 32768;
  char* sB0 = smem + 65536;
  char* sB1 = smem + 65536 + 32768;

  // ---- prologue: t0+t1 resident (B-h0(1) staged at P1 of t=0)
  if constexpr (ACVT) {
    a32_issue(A32b, lda, 0, wid, lane, va);       // 8 A-loads t0
    stage_half(Bb, ldb, 0, sB0, 0, wid, lane);    // 6 B-gloads
    stage_half(Bb, ldb, 0, sB0, 1, wid, lane);
    stage_half(Bb, ldb, 1, sB1, 1, wid, lane);
    asm volatile("s_waitcnt vmcnt(6)" ::: "memory");  // drain A(t0), keep B6
    a32_write(sA0, wid, lane, va);
    a32_issue(A32b, lda, 1, wid, lane, va);       // 8 A-loads t1
    asm volatile("s_waitcnt vmcnt(0)" ::: "memory");
    a32_write(sA1, wid, lane, va);
    __syncthreads();
  } else {
    stage_half(Ab, lda, 0, sA0, 0, wid, lane);
    stage_half(Bb, ldb, 0, sB0, 1, wid, lane);
    stage_half(Ab, lda, 0, sA0, 1, wid, lane);
    stage_half(Bb, ldb, 0, sB0, 0, wid, lane);
    stage_half(Ab, lda, 1, sA1, 0, wid, lane);
    stage_half(Bb, ldb, 1, sB1, 1, wid, lane);
    stage_half(Ab, lda, 1, sA1, 1, wid, lane);
    asm volatile("s_waitcnt vmcnt(6)" ::: "memory");  // drain t0, keep t1's 3
    __builtin_amdgcn_s_barrier();
  }

  for (int t = 0; t < NT; ++t) {
    const int p = t & 1, q = p ^ 1;
    char* sAc = smem + p * 32768;
    char* sBc = smem + 65536 + p * 32768;
    char* sBq = smem + 65536 + q * 32768;
    // clamped tail keeps issue counts uniform; duplicate writes land in
    // dead-or-identical slots only.
    const int u1 = (t + 1 < NT) ? t + 1 : NT - 1;
    const int u2 = (t + 2 < NT) ? t + 2 : NT - 1;

    // ---- P1: Q(0,0)
    lda_frags<0>(sAc, wr, lo, hi, af);
    ldb_frags<0>(sBc, wc, lo, hi, bf0);
    stage_half(Bb, ldb, u1, sBq, 0, wid, lane);  // B-h0(t+1) -> q
    __builtin_amdgcn_s_barrier();
    asm volatile("s_waitcnt lgkmcnt(0)" ::: "memory");
    mfma_quad<0, 0>(af, bf0, acc);
    __builtin_amdgcn_s_barrier();

    // ---- P2: Q(0,1)  (A0 slot dead)
    ldb_frags<1>(sBc, wc, lo, hi, bf1);
    if constexpr (ACVT)
      a32_issue(A32b, lda, u2, wid, lane, va);   // fp32 A(t+2) -> regs
    else
      stage_half(Ab, lda, u2, sAc, 0, wid, lane);
    __builtin_amdgcn_s_barrier();
    asm volatile("s_waitcnt lgkmcnt(0)" ::: "memory");
    mfma_quad<0, 1>(af, bf1, acc);
    __builtin_amdgcn_s_barrier();

    // ---- P3: Q(1,1)  (B1 slot dead)
    lda_frags<1>(sAc, wr, lo, hi, af);
    stage_half(Bb, ldb, u2, sBc, 1, wid, lane);  // B-h1(t+2) -> p
    __builtin_amdgcn_s_barrier();
    asm volatile("s_waitcnt lgkmcnt(0)" ::: "memory");
    mfma_quad<2, 1>(af, bf1, acc);
    __builtin_amdgcn_s_barrier();

    // ---- P4: Q(1,0)  (A1 slot dead; bf0 reused from regs)
    if constexpr (ACVT) {
      // drain: A-loads(P2,t) + B gloads(P1,t) + older; keep P3(t)'s 2.
      asm volatile("s_waitcnt vmcnt(2)" ::: "memory");
      a32_write(sAc, wid, lane, va);             // A(t+2) -> A[p], both halves
    } else {
      stage_half(Ab, lda, u2, sAc, 1, wid, lane);
      asm volatile("s_waitcnt vmcnt(6)" ::: "memory");
    }
    __builtin_amdgcn_s_barrier();
    asm volatile("s_waitcnt lgkmcnt(0)" ::: "memory");
    mfma_quad<2, 0>(af, bf0, acc);
    __builtin_amdgcn_s_barrier();
  }

  asm volatile("s_waitcnt vmcnt(0)" ::: "memory");

  // epilogue: 32x32 C/D layout col = lo, row = (e&3) + 8*(e>>2) + 4*hi
#pragma unroll
  for (int mi = 0; mi < 4; ++mi) {
    const int r0 = (mi >> 1) * 128 + wr * 64 + (mi & 1) * 32 + 4 * hi;
#pragma unroll
    for (int ni = 0; ni < 2; ++ni) {
      const int cc = (int)n0 + ni * 128 + wc * 32 + lo;
#pragma unroll
      for (int e = 0; e < 16; ++e) {
        const long row = m0 + r0 + (e & 3) + 8 * (e >> 2);
        float v = acc[mi][ni][e];
        if constexpr (BIAS == 1) v += bias[bz * biasStride + cc];
        if constexpr (BIAS == 2) v += bias[(int)row];
        C[row * (long)ldc + cc] = (OT)v;
      }
    }
  }
}

// ===================== auxiliary kernels =====================

// fp32 -> fp16 for emoji only (meme/text are converted inside the proj GEMM)
__global__ __launch_bounds__(256) void convert_e(const float* __restrict__ x,
                                                 _Float16* __restrict__ out) {
  int i = blockIdx.x * 256 + threadIdx.x;  // 4194304 chunks
  floatx4 v = ((const floatx4*)x)[i];
  half4_t h = {(_Float16)v[0], (_Float16)v[1], (_Float16)v[2], (_Float16)v[3]};
  ((half4_t*)out)[i] = h;
}

__global__ __launch_bounds__(256) void convert_w(const float* __restrict__ Wq,
                                                 const float* __restrict__ Wk,
                                                 const float* __restrict__ Wv,
                                                 _Float16* __restrict__ out) {
  int i = blockIdx.x * 256 + threadIdx.x;  // 786432 chunks total
  int t = i >> 18;                         // 262144 chunks per tensor
  int j = i & 262143;
  const float* src = (t == 0) ? Wq : (t == 1) ? Wk : Wv;
  floatx4 v = ((const floatx4*)src)[j];
  half4_t h = {(_Float16)v[0], (_Float16)v[1], (_Float16)v[2], (_Float16)v[3]};
  ((half4_t*)out)[i] = h;
}

__global__ __launch_bounds__(256) void pack_bias(const float* __restrict__ bq,
                                                 const float* __restrict__ bk,
                                                 const float* __restrict__ bv,
                                                 float* __restrict__ out) {
  int b = blockIdx.x;
  const float* src = (b == 0) ? bq : (b == 1) ? bk : bv;
  ((floatx4*)out)[b * 256 + threadIdx.x] =
      ((const floatx4*)src)[threadIdx.x];
}

// Row softmax over 1024 fp16 scores, fp32 math, fp16 result in place.
__global__ __launch_bounds__(256) void softmax_rows_h(_Float16* __restrict__ S) {
  long row = blockIdx.x;
  _Float16* Sr = S + row * 1024;
  int tid = threadIdx.x, lane = tid & 63, wid = tid >> 6;
  half4_t x = ((const half4_t*)Sr)[tid];
  float x0 = x[0], x1 = x[1], x2 = x[2], x3 = x[3];
  float mx = fmaxf(fmaxf(x0, x1), fmaxf(x2, x3));
#pragma unroll
  for (int off = 32; off > 0; off >>= 1) mx = fmaxf(mx, __shfl_xor(mx, off));
  __shared__ float redm[4];
  if (lane == 0) redm[wid] = mx;
  __syncthreads();
  mx = fmaxf(fmaxf(redm[0], redm[1]), fmaxf(redm[2], redm[3]));
  float e0 = __expf(x0 - mx), e1 = __expf(x1 - mx);
  float e2 = __expf(x2 - mx), e3 = __expf(x3 - mx);
  float s = e0 + e1 + e2 + e3;
#pragma unroll
  for (int off = 32; off > 0; off >>= 1) s += __shfl_xor(s, off);
  __shared__ float reds[4];
  if (lane == 0) reds[wid] = s;
  __syncthreads();
  s = reds[0] + reds[1] + reds[2] + reds[3];
  float inv = 1.0f / s;
  half4_t h = {(_Float16)(e0 * inv), (_Float16)(e1 * inv),
               (_Float16)(e2 * inv), (_Float16)(e3 * inv)};
  ((half4_t*)Sr)[tid] = h;
}

extern "C" void kernel_launch(void* const* d_in, const int* in_sizes, int n_in,
                              void* d_out, int out_size, void* d_ws,
                              size_t ws_size, hipStream_t stream) {
  (void)in_sizes; (void)n_in; (void)out_size; (void)ws_size;
  const float* meme  = (const float*)d_in[0];
  const float* text  = (const float*)d_in[1];
  const float* emoji = (const float*)d_in[2];
  const float* Wq = (const float*)d_in[3];
  const float* bq = (const float*)d_in[4];
  const float* Wk = (const float*)d_in[5];
  const float* bk = (const float*)d_in[6];
  const float* Wv = (const float*)d_in[7];
  const float* bv = (const float*)d_in[8];

  const long MB = 1024 * 1024;
  char* ws = (char*)d_ws;
  // [0,6) MB:    hWq/hWk/hWv fp16     [6,7): packed bias fp32
  // [7,39) MB:   S (fp16 scores, 32MB)
  // [39,71) MB:  Vt (fp16, 32MB)
  // [71,103) MB: emoji_h fp16
  // [103,135):   Qh fp16   [135,167): Kh fp16
  _Float16* hWq = (_Float16*)ws;
  float* pbias  = (float*)(ws + 6 * MB);
  _Float16* S   = (_Float16*)(ws + 7 * MB);
  _Float16* Vt  = (_Float16*)(ws + 39 * MB);
  _Float16* eh  = (_Float16*)(ws + 71 * MB);
  _Float16* Qh  = (_Float16*)(ws + 103 * MB);
  _Float16* Kh  = (_Float16*)(ws + 135 * MB);
  _Float16* hWk = hWq + 1 * MB;
  _Float16* hWv = hWq + 2 * MB;

  dim3 blk(256), blk5(512);
  convert_w<<<3072, blk, 0, stream>>>(Wq, Wk, Wv, hWq);
  pack_bias<<<3, blk, 0, stream>>>(bq, bk, bv, pbias);
  convert_e<<<16384, blk, 0, stream>>>(emoji, eh);

  // Q projection: A = fp32 meme (converted in-kernel). M=16384, N=1024.
  // SEPARATE launches per input buffer (meme/text are distinct allocations).
  gemm256<_Float16, 1, 4, 64, 1><<<dim3(256), blk5, 0, stream>>>(
      nullptr, meme, 0, 1024, hWq, 0, 1024, Qh, 0, 1024, pbias, 0);
  // K projection: A = fp32 text.
  gemm256<_Float16, 1, 4, 64, 1><<<dim3(256), blk5, 0, stream>>>(
      nullptr, text, 0, 1024, hWk, 0, 1024, Kh, 0, 1024, pbias + 1024, 0);
  // Vt[a, b*L+l] = sum_h Wv[a,h]*emoji[b,l,h] + bv[a]  (V transposed)
  gemm256<_Float16, 2, 64, 4, 0><<<dim3(256), blk5, 0, stream>>>(
      hWv, nullptr, 0, 1024, eh, 0, 1024, Vt, 0, 16384, pbias + 2048, 0);
  // S[b] = Q[b] @ K[b]^T -> fp16. per-batch 1024x1024, z=16.
  gemm256<_Float16, 0, 4, 4, 0><<<dim3(256), blk5, 0, stream>>>(
      Qh, nullptr, 1048576, 1024, Kh, 1048576, 1024, S, 1048576, 1024,
      nullptr, 0);
  // softmax rows, fp16 in place
  softmax_rows_h<<<16384, blk, 0, stream>>>(S);
  // O[b] = P[b] @ V[b] via Vt: C[q,a] = sum_k P[q,k] * Vt[a, b*1024+k]
  gemm256<float, 0, 4, 4, 0><<<dim3(256), blk5, 0, stream>>>(
      S, nullptr, 1048576, 1024, Vt, 1024, 16384, (float*)d_out, 1048576,
      1024, nullptr, 0);
}

// Round 7
// 444.856 us; speedup vs baseline: 1.1443x; 1.1443x over previous
//
#include <hip/hip_runtime.h>

typedef _Float16 half8_t __attribute__((ext_vector_type(8)));
typedef _Float16 half4_t __attribute__((ext_vector_type(4)));
typedef float floatx4 __attribute__((ext_vector_type(4)));
typedef float f32x16 __attribute__((ext_vector_type(16)));

// async global->LDS, 16B per lane. lds ptr wave-uniform; HW writes lane L at
// ldsbase + L*16.
__device__ inline void gload16(const void* g, void* l) {
  __builtin_amdgcn_global_load_lds(
      (const __attribute__((address_space(1))) unsigned int*)g,
      (__attribute__((address_space(3))) unsigned int*)l, 16, 0, 0);
}

// ============ 256x256 BT GEMM, 32x32x16 MFMA, coalesced staging ==========
// C[m,n] = sum_h A[m,h]*B[n,h] (+bias). K=1024 = 16 tiles of BK=64.
// 512 threads = 8 waves in 2(wr) x 4(wc); per phase all waves compute one
// 128x128 C-quadrant; per-wave slice 64x32.
//
// LDS layout (per operand per parity, 32 KB = 2048 x 16B chunks):
//   slot(m, kb) = m*8 + (kb ^ (m&7)),  kb = k/8   [XOR involution, both
//   sides: staging global src is pre-permuted, frag reads apply same XOR]
// STAGING IS COALESCED: instruction (wid,h,i) covers chunks c0..c0+63,
// c0 = h*1024 + wid*128 + i*64. Lane L -> row m = c0/8 + L/8,
// kb = (L&7)^(L/8). 8-lane groups read one aligned 128B row segment
// (8 x 128B transactions/instr vs 64 x 16B scattered before — the r0-r6
// staging scatter was the dominant cost, ~4-6k cyc/K-tile of transactions).
// Per-lane global offset is lane-constant: (L>>3)*ld + ((L&7)^(L>>3))*8.
//
// Frag reads (32x32x16, lane L: lo=L&31, hi=L>>5):
//   A[row0+lo][ks*16+hi*8+j] -> byte (row0+lo)*128 + ((ks*2+hi)^(lo&7))*16
//   4-way bank conflict (rows 8 apart share banks) ~1.58x — accepted.
//   C/D: col = lo, row = (e&3) + 8*(e>>2) + 4*hi   [m74/m101]
//
// Phases (r2's twice-proven skeleton; bf0 kept in regs P1->P4):
//   P1 Q00: lda A0, ldb B0->bf0; stage B-h0(t+1)->q
//   P2 Q01: ldb B1->bf1;         stage A-h0(t+2)->p  (A0 dead)
//   P3 Q11: lda A1;              stage B-h1(t+2)->p  (B1 dead)
//   P4 Q10: stage A-h1(t+2)->p (A1 dead); vmcnt(6)
// vmcnt(6) at P4 drains everything tile t+1 needs; never 0 in the loop.
constexpr int NT = 16;  // K / 64

__device__ inline void lda_frags2(const char* sA, int rb, const int* xk,
                                  half8_t af[2][4]) {
#pragma unroll
  for (int mp = 0; mp < 2; ++mp)
#pragma unroll
    for (int ks = 0; ks < 4; ++ks)
      af[mp][ks] = *(const half8_t*)(
          sA + (size_t)((rb + mp * 32) * 128 + xk[ks] * 16));
}

__device__ inline void ldb_frags2(const char* sB, int cb, const int* xk,
                                  half8_t bf[4]) {
#pragma unroll
  for (int ks = 0; ks < 4; ++ks)
    bf[ks] = *(const half8_t*)(sB + (size_t)(cb * 128 + xk[ks] * 16));
}

// one C-quadrant: 2 m-pos x 4 k-steps of 32x32x16
template <int MQ, int NI>
__device__ inline void mfma_quad(const half8_t af[2][4], const half8_t bf[4],
                                 f32x16 acc[4][2]) {
  __builtin_amdgcn_s_setprio(1);
#pragma unroll
  for (int mp = 0; mp < 2; ++mp)
#pragma unroll
    for (int ks = 0; ks < 4; ++ks)
      acc[MQ + mp][NI] = __builtin_amdgcn_mfma_f32_32x32x16_f16(
          af[mp][ks], bf[ks], acc[MQ + mp][NI], 0, 0, 0);
  __builtin_amdgcn_s_setprio(0);
}

// stage half h (rows [h*128,h*128+128)) of K-tile u of operand X (X already
// includes the block tile offset). laneoff = (L>>3)*ld + ((L&7)^(L>>3))*8.
__device__ inline void stage_half(const _Float16* __restrict__ X, long laneoff,
                                  int ldx, int u, char* opbase, int h,
                                  int wid) {
#pragma unroll
  for (int i = 0; i < 2; ++i) {
    const int c0 = h * 1024 + wid * 128 + i * 64;
    gload16(X + (long)(c0 >> 3) * ldx + u * 64 + laneoff,
            opbase + (size_t)c0 * 16);
  }
}

template <typename OT, int BIAS, int GX, int GY>
__global__ __launch_bounds__(512, 2) void gemm256(
    const _Float16* __restrict__ A, long As, int lda,
    const _Float16* __restrict__ B, long Bs, int ldb,
    OT* __restrict__ C, long Cs, int ldc, const float* __restrict__ bias,
    int biasStride) {
  __shared__ char smem[131072];  // A: p*32768, B: 65536 + p*32768

  // XCD chunk swizzle (grids are 256/512, always %8==0)
  const int id = blockIdx.x;
  const int chunk = gridDim.x >> 3;
  const int nid = (id & 7) * chunk + (id >> 3);
  const int bx = nid % GX;
  const int by = (nid / GX) % GY;
  const int bz = nid / (GX * GY);

  const int tid = threadIdx.x;
  const int lane = tid & 63;
  const int wid = tid >> 6;
  const int wr = wid >> 2;   // 0..1
  const int wc = wid & 3;    // 0..3
  const int lo = lane & 31;
  const int hi = lane >> 5;
  const int l7 = lane & 7;
  const int l8 = lane >> 3;
  const long laneA = (long)l8 * lda + ((l7 ^ l8) << 3);
  const long laneB = (long)l8 * ldb + ((l7 ^ l8) << 3);
  // frag-read slot XOR per k-slice (involution partner of the staging perm)
  int xk[4];
#pragma unroll
  for (int ks = 0; ks < 4; ++ks) xk[ks] = (ks * 2 + hi) ^ l7;

  const long m0 = (long)by * 256;
  const long n0 = (long)bx * 256;
  const _Float16* Ab = A + (long)bz * As + m0 * (long)lda;
  const _Float16* Bb = B + (long)bz * Bs + n0 * (long)ldb;
  C += (long)bz * Cs;

  f32x16 acc[4][2] = {};
  half8_t af[2][4], bf0[4], bf1[4];

  char* sA0 = smem;
  char* sA1 = smem + 32768;
  char* sB0 = smem + 65536;
  char* sB1 = smem + 65536 + 32768;

  // ---- prologue: t0 fully + t1 partially resident (B-h0(t1) staged P1(t0))
  stage_half(Ab, laneA, lda, 0, sA0, 0, wid);
  stage_half(Bb, laneB, ldb, 0, sB0, 1, wid);
  stage_half(Ab, laneA, lda, 0, sA0, 1, wid);
  stage_half(Bb, laneB, ldb, 0, sB0, 0, wid);
  stage_half(Ab, laneA, lda, 1, sA1, 0, wid);
  stage_half(Bb, laneB, ldb, 1, sB1, 1, wid);
  stage_half(Ab, laneA, lda, 1, sA1, 1, wid);
  asm volatile("s_waitcnt vmcnt(6)" ::: "memory");  // drain t0, keep t1's 3
  __builtin_amdgcn_s_barrier();

  for (int t = 0; t < NT; ++t) {
    const int p = t & 1, q = p ^ 1;
    char* sAc = smem + p * 32768;
    char* sBc = smem + 65536 + p * 32768;
    char* sBq = smem + 65536 + q * 32768;
    // clamped tail keeps issue counts uniform; duplicate writes land in
    // dead-or-identical slots only.
    const int u1 = (t + 1 < NT) ? t + 1 : NT - 1;
    const int u2 = (t + 2 < NT) ? t + 2 : NT - 1;

    // ---- P1: Q(0,0)
    lda_frags2(sAc, wr * 64 + lo, xk, af);
    ldb_frags2(sBc, wc * 32 + lo, xk, bf0);
    stage_half(Bb, laneB, ldb, u1, sBq, 0, wid);  // B-h0(t+1) -> q
    __builtin_amdgcn_s_barrier();
    asm volatile("s_waitcnt lgkmcnt(0)" ::: "memory");
    mfma_quad<0, 0>(af, bf0, acc);
    __builtin_amdgcn_s_barrier();

    // ---- P2: Q(0,1)  (A0 slot dead)
    ldb_frags2(sBc, 128 + wc * 32 + lo, xk, bf1);
    stage_half(Ab, laneA, lda, u2, sAc, 0, wid);  // A-h0(t+2) -> p
    __builtin_amdgcn_s_barrier();
    asm volatile("s_waitcnt lgkmcnt(0)" ::: "memory");
    mfma_quad<0, 1>(af, bf1, acc);
    __builtin_amdgcn_s_barrier();

    // ---- P3: Q(1,1)  (B1 slot dead)
    lda_frags2(sAc, 128 + wr * 64 + lo, xk, af);
    stage_half(Bb, laneB, ldb, u2, sBc, 1, wid);  // B-h1(t+2) -> p
    __builtin_amdgcn_s_barrier();
    asm volatile("s_waitcnt lgkmcnt(0)" ::: "memory");
    mfma_quad<2, 1>(af, bf1, acc);
    __builtin_amdgcn_s_barrier();

    // ---- P4: Q(1,0)  (A1 slot dead; bf0 reused from regs)
    stage_half(Ab, laneA, lda, u2, sAc, 1, wid);  // A-h1(t+2) -> p
    asm volatile("s_waitcnt vmcnt(6)" ::: "memory");
    __builtin_amdgcn_s_barrier();
    asm volatile("s_waitcnt lgkmcnt(0)" ::: "memory");
    mfma_quad<2, 0>(af, bf0, acc);
    __builtin_amdgcn_s_barrier();
  }

  asm volatile("s_waitcnt vmcnt(0)" ::: "memory");

  // epilogue: 32x32 C/D layout col = lo, row = (e&3) + 8*(e>>2) + 4*hi
#pragma unroll
  for (int mi = 0; mi < 4; ++mi) {
    const int r0 = (mi >> 1) * 128 + wr * 64 + (mi & 1) * 32 + 4 * hi;
#pragma unroll
    for (int ni = 0; ni < 2; ++ni) {
      const int cc = (int)n0 + ni * 128 + wc * 32 + lo;
#pragma unroll
      for (int e = 0; e < 16; ++e) {
        const long row = m0 + r0 + (e & 3) + 8 * (e >> 2);
        float v = acc[mi][ni][e];
        if constexpr (BIAS == 1) v += bias[bz * biasStride + cc];
        if constexpr (BIAS == 2) v += bias[(int)row];
        C[row * (long)ldc + cc] = (OT)v;
      }
    }
  }
}

// ===================== auxiliary kernels =====================

// fp32 -> fp16, one float4 chunk per thread, 3 tensors of 16M floats each.
__global__ __launch_bounds__(256) void convert_x(const float* __restrict__ x0,
                                                 const float* __restrict__ x1,
                                                 const float* __restrict__ x2,
                                                 _Float16* __restrict__ out) {
  int i = blockIdx.x * 256 + threadIdx.x;  // 12582912 chunks total
  int t = i >> 22;                         // 4194304 chunks per tensor
  int j = i & 4194303;
  const float* src = (t == 0) ? x0 : (t == 1) ? x1 : x2;
  floatx4 v = ((const floatx4*)src)[j];
  half4_t h = {(_Float16)v[0], (_Float16)v[1], (_Float16)v[2], (_Float16)v[3]};
  ((half4_t*)out)[i] = h;
}

__global__ __launch_bounds__(256) void convert_w(const float* __restrict__ Wq,
                                                 const float* __restrict__ Wk,
                                                 const float* __restrict__ Wv,
                                                 _Float16* __restrict__ out) {
  int i = blockIdx.x * 256 + threadIdx.x;  // 786432 chunks total
  int t = i >> 18;                         // 262144 chunks per tensor
  int j = i & 262143;
  const float* src = (t == 0) ? Wq : (t == 1) ? Wk : Wv;
  floatx4 v = ((const floatx4*)src)[j];
  half4_t h = {(_Float16)v[0], (_Float16)v[1], (_Float16)v[2], (_Float16)v[3]};
  ((half4_t*)out)[i] = h;
}

__global__ __launch_bounds__(256) void pack_bias(const float* __restrict__ bq,
                                                 const float* __restrict__ bk,
                                                 const float* __restrict__ bv,
                                                 float* __restrict__ out) {
  int b = blockIdx.x;
  const float* src = (b == 0) ? bq : (b == 1) ? bk : bv;
  ((floatx4*)out)[b * 256 + threadIdx.x] =
      ((const floatx4*)src)[threadIdx.x];
}

// Row softmax over 1024 fp16 scores, fp32 math, fp16 result in place.
__global__ __launch_bounds__(256) void softmax_rows_h(_Float16* __restrict__ S) {
  long row = blockIdx.x;
  _Float16* Sr = S + row * 1024;
  int tid = threadIdx.x, lane = tid & 63, wid = tid >> 6;
  half4_t x = ((const half4_t*)Sr)[tid];
  float x0 = x[0], x1 = x[1], x2 = x[2], x3 = x[3];
  float mx = fmaxf(fmaxf(x0, x1), fmaxf(x2, x3));
#pragma unroll
  for (int off = 32; off > 0; off >>= 1) mx = fmaxf(mx, __shfl_xor(mx, off));
  __shared__ float redm[4];
  if (lane == 0) redm[wid] = mx;
  __syncthreads();
  mx = fmaxf(fmaxf(redm[0], redm[1]), fmaxf(redm[2], redm[3]));
  float e0 = __expf(x0 - mx), e1 = __expf(x1 - mx);
  float e2 = __expf(x2 - mx), e3 = __expf(x3 - mx);
  float s = e0 + e1 + e2 + e3;
#pragma unroll
  for (int off = 32; off > 0; off >>= 1) s += __shfl_xor(s, off);
  __shared__ float reds[4];
  if (lane == 0) reds[wid] = s;
  __syncthreads();
  s = reds[0] + reds[1] + reds[2] + reds[3];
  float inv = 1.0f / s;
  half4_t h = {(_Float16)(e0 * inv), (_Float16)(e1 * inv),
               (_Float16)(e2 * inv), (_Float16)(e3 * inv)};
  ((half4_t*)Sr)[tid] = h;
}

extern "C" void kernel_launch(void* const* d_in, const int* in_sizes, int n_in,
                              void* d_out, int out_size, void* d_ws,
                              size_t ws_size, hipStream_t stream) {
  (void)in_sizes; (void)n_in; (void)out_size; (void)ws_size;
  const float* meme  = (const float*)d_in[0];
  const float* text  = (const float*)d_in[1];
  const float* emoji = (const float*)d_in[2];
  const float* Wq = (const float*)d_in[3];
  const float* bq = (const float*)d_in[4];
  const float* Wk = (const float*)d_in[5];
  const float* bk = (const float*)d_in[6];
  const float* Wv = (const float*)d_in[7];
  const float* bv = (const float*)d_in[8];

  const long MB = 1024 * 1024;
  char* ws = (char*)d_ws;
  // [0,6) MB:    hWq/hWk/hWv fp16 (contiguous, stride 1M halves)
  // [6,7):       packed bias 3*1024 fp32
  // [7,39) MB:   meme_h  -> dead after QK GEMM -> reused as S (fp16, 32MB)
  // [39,71) MB:  text_h  -> dead after QK GEMM -> reused as Vt (fp16, 32MB)
  // [71,103) MB: emoji_h -> dead after Vt GEMM
  // [103,135):   Qh fp16   [135,167): Kh fp16
  _Float16* hWq = (_Float16*)ws;
  float* pbias  = (float*)(ws + 6 * MB);
  _Float16* mh  = (_Float16*)(ws + 7 * MB);
  _Float16* th  = (_Float16*)(ws + 39 * MB);
  _Float16* eh  = (_Float16*)(ws + 71 * MB);
  _Float16* Qh  = (_Float16*)(ws + 103 * MB);
  _Float16* Kh  = (_Float16*)(ws + 135 * MB);
  _Float16* S   = mh;  // aliases meme_h (dead by then)
  _Float16* Vt  = th;  // aliases text_h (dead by then)
  _Float16* hWv = hWq + 2 * MB;

  dim3 blk(256), blk5(512);
  convert_w<<<3072, blk, 0, stream>>>(Wq, Wk, Wv, hWq);
  pack_bias<<<3, blk, 0, stream>>>(bq, bk, bv, pbias);
  convert_x<<<49152, blk, 0, stream>>>(meme, text, emoji, mh);

  // Q,K projections batched (z=2, contiguous workspace): M=16384, N=1024.
  gemm256<_Float16, 1, 4, 64><<<dim3(512), blk5, 0, stream>>>(
      mh, 16777216, 1024, hWq, 1048576, 1024, Qh, 16777216, 1024, pbias, 1024);
  // Vt[a, b*L+l] = sum_h Wv[a,h]*emoji[b,l,h] + bv[a]  (V transposed)
  gemm256<_Float16, 2, 64, 4><<<dim3(256), blk5, 0, stream>>>(
      hWv, 0, 1024, eh, 0, 1024, Vt, 0, 16384, pbias + 2048, 0);
  // S[b] = Q[b] @ K[b]^T -> fp16. per-batch 1024x1024, z=16.
  gemm256<_Float16, 0, 4, 4><<<dim3(256), blk5, 0, stream>>>(
      Qh, 1048576, 1024, Kh, 1048576, 1024, S, 1048576, 1024, nullptr, 0);
  // softmax rows, fp16 in place
  softmax_rows_h<<<16384, blk, 0, stream>>>(S);
  // O[b] = P[b] @ V[b] via Vt: C[q,a] = sum_k P[q,k] * Vt[a, b*1024+k]
  gemm256<float, 0, 4, 4><<<dim3(256), blk5, 0, stream>>>(
      S, 1048576, 1024, Vt, 1024, 16384, (float*)d_out, 1048576, 1024,
      nullptr, 0);
}